// Round 14
// baseline (51.800 us; speedup 1.0000x reference)
//
#include <hip/hip_runtime.h>
#include <math.h>

constexpr int BATCH = 4096;
constexpr int DIM   = 2048;
constexpr int REPS  = 8;
constexpr float INV2PI = 0.15915494309189535f;  // 1/(2*pi)

constexpr int TPB   = 256;
constexpr int GRIDX = DIM / TPB;       // 8
constexpr int GRIDY = 256;             // 2048 blocks = 8 blocks/CU
constexpr int BPB   = BATCH / GRIDY;   // 16 rows per block
constexpr int ILP   = 2;
constexpr int NCH   = BPB / ILP;       // 8 chunks

constexpr int TBL   = 1024;            // table entries per period

__global__ __launch_bounds__(TPB, 4)
void daruan_kernel(const float* __restrict__ x,       // (BATCH, DIM)
                   const float* __restrict__ theta,   // (DIM, 9, 2)
                   const float* __restrict__ paw,     // (DIM, 8)
                   const float* __restrict__ pab,     // (DIM, 8)
                   const float* __restrict__ postw,   // (DIM)
                   const float* __restrict__ postb,   // (DIM)
                   float* __restrict__ out)           // (BATCH, DIM)
{
    // (sin, cos) pairs over one period, +1 entry so lerp never wraps. 8.2 KB.
    __shared__ float2 tbl[TBL + 1];
    const int t = threadIdx.x;
    const int d = blockIdx.x * TPB + t;             // lane-per-d: coalesced

    // ---- build the table (hw trans, once per block, amortized 4096x) ----
    for (int k = t; k <= TBL; k += TPB) {
        const float f = (float)k * (1.0f / TBL);    // revolutions
        tbl[k] = make_float2(__builtin_amdgcn_sinf(f), __builtin_amdgcn_cosf(f));
    }

    // ---- per-d preamble (R2-proven folding): RZ(t0[0])+RY(t1[0]) -> initial
    // Bloch state; RZ(t0[r+1]) (incl. final) -> rep r's encoding bias.
    const float* th = theta + (size_t)d * 18;
    const float t00 = th[0] * INV2PI;
    const float X0  = __builtin_amdgcn_cosf(t00);
    const float Y0  = __builtin_amdgcn_sinf(t00);
    const float t10 = th[1] * INV2PI;
    const float Xi  = X0 * __builtin_amdgcn_cosf(t10);
    const float Yi  = Y0;
    const float Zi  = -X0 * __builtin_amdgcn_sinf(t10);

    float cy[REPS], sy[REPS], wr[REPS], br[REPS];
#pragma unroll
    for (int k = 0; k < REPS; ++k) {
        const float t1 = th[2 * k + 3] * INV2PI;        // theta1[k+1]
        cy[k] = __builtin_amdgcn_cosf(t1);
        sy[k] = __builtin_amdgcn_sinf(t1);
        wr[k] = paw[(size_t)d * REPS + k] * INV2PI;
        br[k] = (pab[(size_t)d * REPS + k] + th[2 * (k + 1)]) * INV2PI;
    }
    const float pw = postw[d];
    const float pb = postb[d];

    __syncthreads();   // table ready

    // LUT sincos of 2*pi*e (e in revolutions): ~10 VALU + 2 ds_read_b64
    auto lut_sincos = [&](float e, float& s, float& c) {
        const float tt = e - floorf(e);          // [0,1)
        const float ft = tt * (float)TBL;        // [0,1024)
        const float fi = floorf(ft);
        const float a  = ft - fi;                // lerp weight
        const int   i  = (int)fi;                // 0..1023
        const float2 p0 = tbl[i];                // ds_read_b64
        const float2 p1 = tbl[i + 1];            // ds_read_b64 offset:8
        s = fmaf(a, p1.x - p0.x, p0.x);
        c = fmaf(a, p1.y - p0.y, p0.y);
    };

    const int bbase = blockIdx.y * BPB;
    const float* xp = x + (size_t)bbase * DIM + d;
    float* op = out + (size_t)bbase * DIM + d;

    auto do_elem = [&](float xv) -> float {
        // all 16 lookups issued up front (angles independent of state)
        float se[REPS], ce[REPS];
#pragma unroll
        for (int r = 0; r < REPS; ++r)
            lut_sincos(fmaf(wr[r], xv, br[r]), se[r], ce[r]);
        // pure-fma state chain
        float X = fmaf(Xi, ce[0], -Yi * se[0]);
        float Y = fmaf(Xi, se[0],  Yi * ce[0]);
        float Z = Zi;
#pragma unroll
        for (int r = 1; r < REPS; ++r) {
            const float Xb = fmaf(X, cy[r - 1],  Z * sy[r - 1]);
            const float Zb = fmaf(Z, cy[r - 1], -X * sy[r - 1]);
            X = fmaf(Xb, ce[r], -Y * se[r]);
            if (r < REPS - 1)                      // Y dead after last rep
                Y = fmaf(Xb, se[r], Y * ce[r]);
            Z = Zb;
        }
        return fmaf(Z, cy[REPS - 1], -X * sy[REPS - 1]);   // final RY
    };

    float xv[ILP];
#pragma unroll
    for (int i = 0; i < ILP; ++i) xv[i] = xp[(size_t)i * DIM];

#pragma unroll 1
    for (int cc = 0; cc < NCH; ++cc) {
        float xn[ILP];
#pragma unroll
        for (int i = 0; i < ILP; ++i)   // branch-free prefetch (wraps at end)
            xn[i] = xp[(size_t)(((cc + 1) & (NCH - 1)) * ILP + i) * DIM];
#pragma unroll
        for (int i = 0; i < ILP; ++i)
            op[(size_t)(cc * ILP + i) * DIM] = fmaf(do_elem(xv[i]), pw, pb);
#pragma unroll
        for (int i = 0; i < ILP; ++i) xv[i] = xn[i];
    }
}

extern "C" void kernel_launch(void* const* d_in, const int* in_sizes, int n_in,
                              void* d_out, int out_size, void* d_ws, size_t ws_size,
                              hipStream_t stream) {
    const float* x     = (const float*)d_in[0];
    const float* theta = (const float*)d_in[1];
    const float* paw   = (const float*)d_in[2];
    const float* pab   = (const float*)d_in[3];
    const float* postw = (const float*)d_in[4];
    const float* postb = (const float*)d_in[5];
    float* out = (float*)d_out;

    daruan_kernel<<<dim3(GRIDX, GRIDY), dim3(TPB), 0, stream>>>(
        x, theta, paw, pab, postw, postb, out);
}

// Round 15
// 35.439 us; speedup vs baseline: 1.4617x; 1.4617x over previous
//
#include <hip/hip_runtime.h>
#include <math.h>

constexpr int BATCH = 4096;
constexpr int DIM   = 2048;
constexpr int REPS  = 8;
constexpr float INV2PI = 0.15915494309189535f;  // 1/(2*pi)

constexpr int TPB   = 256;
constexpr int GRIDX = DIM / TPB;       // 8
constexpr int GRIDY = 256;             // 2048 blocks = 8 blocks/CU
constexpr int BPB   = BATCH / GRIDY;   // 16 rows per block
constexpr int ILP   = 2;
constexpr int NCH   = BPB / ILP;       // 8 chunks

// Polynomial sincos of 2*pi*f (f in revolutions), |err| ~1e-4, 12 VALU ops,
// zero trans-pipe usage. (R6 coefficients, re-validated.)
__device__ __forceinline__ void poly_sincos(float f, float& s, float& c) {
    const float m = __builtin_rintf(f);
    const float r = f - m;                // |r| <= 0.5
    const float u = r * r;
    float p = fmaf(32.7680000f, u, -74.4701952f);   // sin deg-9 odd
    p = fmaf(p, u, 81.3660160f);
    p = fmaf(p, u, -41.3311104f);
    p = fmaf(p, u, 6.2830536f);
    s = p * r;
    float q = fmaf(45.6130560f, u, -82.3881728f);   // cos deg-8 even
    q = fmaf(q, u, 64.6713088f);
    q = fmaf(q, u, -19.7309120f);
    c = fmaf(q, u, 0.9999527f);
}

__global__ __launch_bounds__(TPB, 4)
void daruan_kernel(const float* __restrict__ x,       // (BATCH, DIM)
                   const float* __restrict__ theta,   // (DIM, 9, 2)
                   const float* __restrict__ paw,     // (DIM, 8)
                   const float* __restrict__ pab,     // (DIM, 8)
                   const float* __restrict__ postw,   // (DIM)
                   const float* __restrict__ postb,   // (DIM)
                   float* __restrict__ out)           // (BATCH, DIM)
{
    const int d = blockIdx.x * TPB + threadIdx.x;   // lane-per-d: coalesced

    // ---- per-d preamble, poly-only (no trans storm). R2-proven folding:
    // RZ(t0[0])+RY(t1[0]) -> initial Bloch state; RZ(t0[r+1]) -> rep r bias.
    const float* th = theta + (size_t)d * 18;
    float s00, c00, s10, c10;
    poly_sincos(th[0] * INV2PI, s00, c00);
    poly_sincos(th[1] * INV2PI, s10, c10);
    const float Xi = c00 * c10;
    const float Yi = s00;
    const float Zi = -c00 * s10;

    float cy[REPS], sy[REPS], wr[REPS], br[REPS];
#pragma unroll
    for (int k = 0; k < REPS; ++k) {
        poly_sincos(th[2 * k + 3] * INV2PI, sy[k], cy[k]);   // theta1[k+1]
        wr[k] = paw[(size_t)d * REPS + k] * INV2PI;
        br[k] = (pab[(size_t)d * REPS + k] + th[2 * (k + 1)]) * INV2PI;
    }
    const float pw = postw[d];
    const float pb = postb[d];

    const int bbase = blockIdx.y * BPB;
    const float* xp = x + (size_t)bbase * DIM + d;
    float* op = out + (size_t)bbase * DIM + d;

    auto do_chunk = [&](const float (&xv)[ILP], int cc) {
        // ---- phase A: ALL 16 angle-pairs as flat independent Horner chains.
        // 32 independent dep-chains; issue (~640cy) >> chain latency (~25cy),
        // so the poly latency is fully hidden — unlike R6's inline form.
        float se[ILP][REPS], ce[ILP][REPS];
#pragma unroll
        for (int i = 0; i < ILP; ++i) {
#pragma unroll
            for (int r = 0; r < REPS; ++r)
                poly_sincos(fmaf(wr[r], xv[i], br[r]), se[i][r], ce[i][r]);
        }
        // ---- phase B: pure-fma state chains (ILP independent) ----
#pragma unroll
        for (int i = 0; i < ILP; ++i) {
            float X = fmaf(Xi, ce[i][0], -Yi * se[i][0]);
            float Y = fmaf(Xi, se[i][0],  Yi * ce[i][0]);
            float Z = Zi;
#pragma unroll
            for (int r = 1; r < REPS; ++r) {
                const float Xb = fmaf(X, cy[r - 1],  Z * sy[r - 1]);
                const float Zb = fmaf(Z, cy[r - 1], -X * sy[r - 1]);
                X = fmaf(Xb, ce[i][r], -Y * se[i][r]);
                if (r < REPS - 1)                      // Y dead after last rep
                    Y = fmaf(Xb, se[i][r], Y * ce[i][r]);
                Z = Zb;
            }
            const float Zf = fmaf(Z, cy[REPS - 1], -X * sy[REPS - 1]);  // final RY
            op[(size_t)(cc * ILP + i) * DIM] = fmaf(Zf, pw, pb);
        }
    };

    float xv[ILP];
#pragma unroll
    for (int i = 0; i < ILP; ++i) xv[i] = xp[(size_t)i * DIM];

#pragma unroll 1
    for (int cc = 0; cc < NCH; ++cc) {
        float xn[ILP];
#pragma unroll
        for (int i = 0; i < ILP; ++i)   // branch-free prefetch (wraps at end)
            xn[i] = xp[(size_t)(((cc + 1) & (NCH - 1)) * ILP + i) * DIM];
        do_chunk(xv, cc);
#pragma unroll
        for (int i = 0; i < ILP; ++i) xv[i] = xn[i];
    }
}

extern "C" void kernel_launch(void* const* d_in, const int* in_sizes, int n_in,
                              void* d_out, int out_size, void* d_ws, size_t ws_size,
                              hipStream_t stream) {
    const float* x     = (const float*)d_in[0];
    const float* theta = (const float*)d_in[1];
    const float* paw   = (const float*)d_in[2];
    const float* pab   = (const float*)d_in[3];
    const float* postw = (const float*)d_in[4];
    const float* postb = (const float*)d_in[5];
    float* out = (float*)d_out;

    daruan_kernel<<<dim3(GRIDX, GRIDY), dim3(TPB), 0, stream>>>(
        x, theta, paw, pab, postw, postb, out);
}